// Round 1
// baseline (243.478 us; speedup 1.0000x reference)
//
#include <hip/hip_runtime.h>

#define N_DIM 8192   // rows of features / columns of w / output length
#define K_DIM 512    // inner dim of features @ E
#define D_DIM 4096   // columns of E / rows of w

typedef __bf16 bf16x8 __attribute__((ext_vector_type(8)));
typedef float  f32x16 __attribute__((ext_vector_type(16)));
typedef unsigned short u16x8 __attribute__((ext_vector_type(8)));

__device__ __forceinline__ unsigned short f2bf(float f) {
    union { float f; unsigned int u; } v; v.f = f;
    unsigned int r = v.u + 0x7FFF + ((v.u >> 16) & 1);   // RNE
    return (unsigned short)(r >> 16);
}

// ---------------------------------------------------------------------------
// Kernel 1: E [512][4096] f32  ->  ET [4096][512] bf16 (k-contiguous rows)
// ---------------------------------------------------------------------------
__global__ __launch_bounds__(256) void transpose_E(const float* __restrict__ E,
                                                   unsigned short* __restrict__ ET) {
    __shared__ float tile[64][65];
    const int d0 = blockIdx.x * 64;
    const int k0 = blockIdx.y * 64;
    const int tid = threadIdx.x;
    const int r  = tid / 16;          // 0..15
    const int c4 = (tid % 16) * 4;    // 0..60
#pragma unroll
    for (int p = 0; p < 4; ++p) {
        int k = p * 16 + r;
        float4 v = *reinterpret_cast<const float4*>(E + (size_t)(k0 + k) * D_DIM + d0 + c4);
        tile[k][c4 + 0] = v.x; tile[k][c4 + 1] = v.y;
        tile[k][c4 + 2] = v.z; tile[k][c4 + 3] = v.w;
    }
    __syncthreads();
#pragma unroll
    for (int p = 0; p < 4; ++p) {
        int d = p * 16 + r;
        ushort4 o;
        o.x = f2bf(tile[c4 + 0][d]);
        o.y = f2bf(tile[c4 + 1][d]);
        o.z = f2bf(tile[c4 + 2][d]);
        o.w = f2bf(tile[c4 + 3][d]);
        *reinterpret_cast<ushort4*>(ET + (size_t)(d0 + d) * K_DIM + k0 + c4) = o;
    }
}

// ---------------------------------------------------------------------------
// Kernel 2: F [8192][512] f32 -> FB bf16, same layout (k-contiguous rows)
// ---------------------------------------------------------------------------
__global__ __launch_bounds__(256) void convert_F(const float* __restrict__ F,
                                                 unsigned short* __restrict__ FB) {
    const int idx8 = (blockIdx.x * 256 + threadIdx.x) * 8;
    float4 a = *reinterpret_cast<const float4*>(F + idx8);
    float4 b = *reinterpret_cast<const float4*>(F + idx8 + 4);
    u16x8 o;
    o[0] = f2bf(a.x); o[1] = f2bf(a.y); o[2] = f2bf(a.z); o[3] = f2bf(a.w);
    o[4] = f2bf(b.x); o[5] = f2bf(b.y); o[6] = f2bf(b.z); o[7] = f2bf(b.w);
    *reinterpret_cast<u16x8*>(FB + idx8) = o;
}

// ---------------------------------------------------------------------------
// Kernel 3: fused  out[n] = sum_d (F@E + b)[n,d] * w[d,n], computed as y^T:
// C-tile 128(d-rows) x 128(n-cols), BK=32, 4 waves (2x2), 32x32x16 bf16 MFMA.
//
// This round: W tile (128x128 f32 = 64 KB) is prefetched into LDS at kernel
// start via non-temporal global_load_lds. The first __syncthreads (vmcnt(0)
// drain) absorbs the HBM wait; with 2 blocks/CU (LDS = 80 KB) the co-resident
// block's K-loop hides it. Epilogue reads W from LDS (conflict-free), so the
// 128 MB W stream now overlaps MFMA instead of serializing in the tail.
// BK=64 -> 32 so Ash+Bsh+Wsh = 8+8+64 = 80 KB keeps occupancy at 2 blocks/CU.
// ---------------------------------------------------------------------------
__global__ __launch_bounds__(256, 2) void gemm_fused(const unsigned short* __restrict__ FB,
                                                     const float* __restrict__ W,
                                                     const unsigned short* __restrict__ ET,
                                                     const float* __restrict__ B,
                                                     float* __restrict__ out) {
    __shared__ unsigned short Ash[128 * 32];  // ET tile: rows = d   (8 KB)
    __shared__ unsigned short Bsh[128 * 32];  // FB tile: rows = n   (8 KB)
    __shared__ float          Wsh[128 * 128]; // W tile [d][n] f32   (64 KB)

    const int tid  = threadIdx.x;
    const int wave = tid >> 6;
    const int lane = tid & 63;
    const int wy   = wave >> 1;     // d-direction wave coord (0..1)
    const int wx   = wave & 1;      // n-direction wave coord (0..1)
    const int l31  = lane & 31;
    const int half = lane >> 5;

    // --- XCD-rectangle swizzle (bijection on 64x32 grid) ---
    const int f   = blockIdx.x + ((int)gridDim.x) * blockIdx.y;  // dispatch order
    const int xcd = f & 7;
    const int s   = f >> 3;               // 0..255 within XCD
    const int ntile = (xcd & 3) * 16 + (s & 15);   // 0..63
    const int dtile = (xcd >> 2) * 16 + (s >> 4);  // 0..31
    const int n0 = ntile * 128;
    const int d0 = dtile * 128;

    // --- W prefetch: whole 128x128 f32 tile -> LDS, issued before the K-loop.
    // Each global_load_lds covers 64 lanes x 16 B = 2 rows (row = 512 B).
    // aux=2 = NT hint: W is read exactly once device-wide, don't evict the
    // FB/ET L2 rectangle.
    {
        const int drow2 = lane >> 5;          // +0/+1 row within the pair
        const int nc    = (lane & 31) * 4;    // f32 column offset
#pragma unroll
        for (int i = 0; i < 16; ++i) {
            const int dr = wave * 32 + i * 2;         // wave-uniform base row
            const float* gw = W + (size_t)(d0 + dr + drow2) * N_DIM + n0 + nc;
            __builtin_amdgcn_global_load_lds(
                (const __attribute__((address_space(1))) void*)gw,
                (__attribute__((address_space(3))) void*)(Wsh + dr * 128),
                16, 0, 2 /* NT */);
        }
    }

    f32x16 acc[2][2] = {};   // [mi=d-tile][ni=n-tile]

    // staging: one global_load_lds(16B) covers 16 rows x 64 B
    const int srow   = lane >> 2;                               // 0..15
    const int schunk = (((lane & 3) ^ ((srow >> 1) & 3)) * 8);  // swizzled chunk (shorts)

    for (int kt = 0; kt < K_DIM / 32; ++kt) {
        const int kb = kt * 32;
#pragma unroll
        for (int jj = 0; jj < 2; ++jj) {
            const int j = wave * 2 + jj;   // 0..7 -> 16 rows each
            const unsigned short* ga =
                ET + (size_t)(d0 + j * 16 + srow) * K_DIM + kb + schunk;
            __builtin_amdgcn_global_load_lds(
                (const __attribute__((address_space(1))) void*)ga,
                (__attribute__((address_space(3))) void*)(Ash + j * 512),
                16, 0, 0);
            const unsigned short* gb =
                FB + (size_t)(n0 + j * 16 + srow) * K_DIM + kb + schunk;
            __builtin_amdgcn_global_load_lds(
                (const __attribute__((address_space(1))) void*)gb,
                (__attribute__((address_space(3))) void*)(Bsh + j * 512),
                16, 0, 0);
        }
        __syncthreads();

#pragma unroll
        for (int ks = 0; ks < 2; ++ks) {
            const int c = ks * 2 + half;   // 16B chunk index within 64 B row
            bf16x8 af[2], bfr[2];
#pragma unroll
            for (int mi = 0; mi < 2; ++mi) {
                const int R = wy * 64 + mi * 32 + l31;
                const int slot = c ^ ((R >> 1) & 3);
                af[mi] = *reinterpret_cast<const bf16x8*>(Ash + R * 32 + slot * 8);
            }
#pragma unroll
            for (int ni = 0; ni < 2; ++ni) {
                const int R = wx * 64 + ni * 32 + l31;
                const int slot = c ^ ((R >> 1) & 3);
                bfr[ni] = *reinterpret_cast<const bf16x8*>(Bsh + R * 32 + slot * 8);
            }
#pragma unroll
            for (int mi = 0; mi < 2; ++mi)
#pragma unroll
                for (int ni = 0; ni < 2; ++ni)
                    acc[mi][ni] = __builtin_amdgcn_mfma_f32_32x32x16_bf16(
                        af[mi], bfr[ni], acc[mi][ni], 0, 0, 0);
        }
        __syncthreads();
    }

    // --- epilogue: C layout 32x32: col(n)=lane&31, row(d)=(reg&3)+8*(reg>>2)+4*half
    // W now comes from LDS (prefetched at start; last barrier guarantees it).
    // Bank check: 32 lanes read 32 consecutive f32 = banks 0..31 per half-wave,
    // two halves (different d-rows) = 2-way alias = free.
    const int nbl = wx * 64;
    const int nb  = n0 + nbl;
    float part0 = 0.f, part1 = 0.f;
#pragma unroll
    for (int mi = 0; mi < 2; ++mi) {
        const int dlb = wy * 64 + mi * 32 + 4 * half;   // local d within tile
#pragma unroll
        for (int reg = 0; reg < 16; ++reg) {
            const int dl = dlb + (reg & 3) + 8 * (reg >> 2);
            const float bd = B[d0 + dl];
            const float* wr = Wsh + dl * 128 + nbl;
            part0 += (acc[mi][0][reg] + bd) * wr[l31];
            part1 += (acc[mi][1][reg] + bd) * wr[32 + l31];
        }
    }
    part0 += __shfl_xor(part0, 32);
    part1 += __shfl_xor(part1, 32);
    if (lane < 32) {
        atomicAdd(out + nb + l31, part0);
        atomicAdd(out + nb + 32 + l31, part1);
    }
}

extern "C" void kernel_launch(void* const* d_in, const int* in_sizes, int n_in,
                              void* d_out, int out_size, void* d_ws, size_t ws_size,
                              hipStream_t stream) {
    const float* F = (const float*)d_in[0];   // features (N, K)
    const float* W = (const float*)d_in[1];   // w        (D, N)
    const float* E = (const float*)d_in[2];   // E        (K, D)
    const float* B = (const float*)d_in[3];   // b        (D,)
    float* out = (float*)d_out;               // (N,) f32

    unsigned short* ET = (unsigned short*)d_ws;                       // 4 MB
    unsigned short* FB = (unsigned short*)((char*)d_ws + (size_t)D_DIM * K_DIM * 2);  // 8 MB

    hipMemsetAsync(d_out, 0, (size_t)out_size * sizeof(float), stream);
    transpose_E<<<dim3(D_DIM / 64, K_DIM / 64), 256, 0, stream>>>(E, ET);
    convert_F<<<dim3(N_DIM * K_DIM / (256 * 8)), 256, 0, stream>>>(F, FB);
    gemm_fused<<<dim3(N_DIM / 128, D_DIM / 128), 256, 0, stream>>>(FB, W, ET, B, out);
}

// Round 2
// 240.451 us; speedup vs baseline: 1.0126x; 1.0126x over previous
//
#include <hip/hip_runtime.h>

#define N_DIM 8192   // rows of features / columns of w / output length
#define K_DIM 512    // inner dim of features @ E
#define D_DIM 4096   // columns of E / rows of w

typedef __bf16 bf16x8 __attribute__((ext_vector_type(8)));
typedef float  f32x16 __attribute__((ext_vector_type(16)));
typedef unsigned short u16x8 __attribute__((ext_vector_type(8)));

__device__ __forceinline__ unsigned short f2bf(float f) {
    union { float f; unsigned int u; } v; v.f = f;
    unsigned int r = v.u + 0x7FFF + ((v.u >> 16) & 1);   // RNE
    return (unsigned short)(r >> 16);
}

// ---------------------------------------------------------------------------
// Kernel 1: E [512][4096] f32  ->  ET [4096][512] bf16 (k-contiguous rows)
// ---------------------------------------------------------------------------
__global__ __launch_bounds__(256) void transpose_E(const float* __restrict__ E,
                                                   unsigned short* __restrict__ ET) {
    __shared__ float tile[64][65];
    const int d0 = blockIdx.x * 64;
    const int k0 = blockIdx.y * 64;
    const int tid = threadIdx.x;
    const int r  = tid / 16;          // 0..15
    const int c4 = (tid % 16) * 4;    // 0..60
#pragma unroll
    for (int p = 0; p < 4; ++p) {
        int k = p * 16 + r;
        float4 v = *reinterpret_cast<const float4*>(E + (size_t)(k0 + k) * D_DIM + d0 + c4);
        tile[k][c4 + 0] = v.x; tile[k][c4 + 1] = v.y;
        tile[k][c4 + 2] = v.z; tile[k][c4 + 3] = v.w;
    }
    __syncthreads();
#pragma unroll
    for (int p = 0; p < 4; ++p) {
        int d = p * 16 + r;
        ushort4 o;
        o.x = f2bf(tile[c4 + 0][d]);
        o.y = f2bf(tile[c4 + 1][d]);
        o.z = f2bf(tile[c4 + 2][d]);
        o.w = f2bf(tile[c4 + 3][d]);
        *reinterpret_cast<ushort4*>(ET + (size_t)(d0 + d) * K_DIM + k0 + c4) = o;
    }
}

// ---------------------------------------------------------------------------
// Kernel 2: F [8192][512] f32 -> FB bf16, same layout (k-contiguous rows)
// ---------------------------------------------------------------------------
__global__ __launch_bounds__(256) void convert_F(const float* __restrict__ F,
                                                 unsigned short* __restrict__ FB) {
    const int idx8 = (blockIdx.x * 256 + threadIdx.x) * 8;
    float4 a = *reinterpret_cast<const float4*>(F + idx8);
    float4 b = *reinterpret_cast<const float4*>(F + idx8 + 4);
    u16x8 o;
    o[0] = f2bf(a.x); o[1] = f2bf(a.y); o[2] = f2bf(a.z); o[3] = f2bf(a.w);
    o[4] = f2bf(b.x); o[5] = f2bf(b.y); o[6] = f2bf(b.z); o[7] = f2bf(b.w);
    *reinterpret_cast<u16x8*>(FB + idx8) = o;
}

// ---------------------------------------------------------------------------
// Kernel 3: fused  out[n] = sum_d (F@E + b)[n,d] * w[d,n], computed as y^T:
// C-tile 128(d-rows) x 128(n-cols), BK=64, 4 waves (2x2), 32x32x16 bf16 MFMA.
//
// Round 2: W -> REGISTERS, spread across the K-loop. Each thread needs exactly
// 64 W scalars (its own acc fragment positions). The kt loop (8 iters) is
// fully unrolled; each iteration issues 8 NT scalar W loads (2 C-regs x
// 2 mi x 2 ni) into statically-indexed wreg[2][16][2]. They fly under the
// ks-loop's ds_read+MFMA and land at the end-of-kt barrier drain (8 KB/block
// per kt instead of a 64 KB head/tail burst). Epilogue is then in-register
// for W. LDS back to 32 KB (BK=64 structure of the 236us baseline).
// ---------------------------------------------------------------------------
__global__ __launch_bounds__(256, 2) void gemm_fused(const unsigned short* __restrict__ FB,
                                                     const float* __restrict__ W,
                                                     const unsigned short* __restrict__ ET,
                                                     const float* __restrict__ B,
                                                     float* __restrict__ out) {
    __shared__ unsigned short Ash[2 * 128 * 32];  // ET tile: rows = d  (16 KB)
    __shared__ unsigned short Bsh[2 * 128 * 32];  // FB tile: rows = n  (16 KB)

    const int tid  = threadIdx.x;
    const int wave = tid >> 6;
    const int lane = tid & 63;
    const int wy   = wave >> 1;     // d-direction wave coord (0..1)
    const int wx   = wave & 1;      // n-direction wave coord (0..1)
    const int l31  = lane & 31;
    const int half = lane >> 5;

    // --- XCD-rectangle swizzle (bijection on 64x32 grid) ---
    const int f   = blockIdx.x + ((int)gridDim.x) * blockIdx.y;  // dispatch order
    const int xcd = f & 7;
    const int s   = f >> 3;               // 0..255 within XCD
    const int ntile = (xcd & 3) * 16 + (s & 15);   // 0..63
    const int dtile = (xcd >> 2) * 16 + (s >> 4);  // 0..31
    const int n0 = ntile * 128;
    const int d0 = dtile * 128;

    f32x16 acc[2][2] = {};       // [mi=d-tile][ni=n-tile]
    float  wreg[2][16][2];       // [mi][reg][ni] -- W values for this thread's acc

    // Per-thread W base: row = d0 + wy*64 + 4*half, col = n0 + wx*64 + l31.
    // Full element: + (mi*32 + (reg&3) + 8*(reg>>2)) * N_DIM + ni*32.
    const float* Wt = W + (size_t)(d0 + wy * 64 + 4 * half) * N_DIM + n0 + wx * 64 + l31;

    // staging: one global_load_lds(16B) covers 16 rows x 64 B
    const int srow   = lane >> 2;                               // 0..15
    const int schunk = (((lane & 3) ^ ((srow >> 1) & 3)) * 8);  // swizzled chunk (shorts)

#pragma unroll
    for (int kt = 0; kt < K_DIM / 64; ++kt) {
        const int kb = kt * 64;
#pragma unroll
        for (int p = 0; p < 2; ++p) {
#pragma unroll
            for (int jj = 0; jj < 2; ++jj) {
                const int j = wave * 2 + jj;   // 0..7 -> 16 rows each
                const unsigned short* ga =
                    ET + (size_t)(d0 + j * 16 + srow) * K_DIM + kb + p * 32 + schunk;
                __builtin_amdgcn_global_load_lds(
                    (const __attribute__((address_space(1))) void*)ga,
                    (__attribute__((address_space(3))) void*)(Ash + p * 4096 + j * 512),
                    16, 0, 0);
                const unsigned short* gb =
                    FB + (size_t)(n0 + j * 16 + srow) * K_DIM + kb + p * 32 + schunk;
                __builtin_amdgcn_global_load_lds(
                    (const __attribute__((address_space(1))) void*)gb,
                    (__attribute__((address_space(3))) void*)(Bsh + p * 4096 + j * 512),
                    16, 0, 0);
            }
        }
        __syncthreads();

        // Issue this kt's slice of W loads (statically indexed after unroll).
        // NT: W is read exactly once device-wide; don't evict the L2 rectangle.
#pragma unroll
        for (int rr = 0; rr < 2; ++rr) {
            const int reg   = kt * 2 + rr;
            const int droff = (reg & 3) + 8 * (reg >> 2);
#pragma unroll
            for (int mi = 0; mi < 2; ++mi)
#pragma unroll
                for (int ni = 0; ni < 2; ++ni)
                    wreg[mi][reg][ni] = __builtin_nontemporal_load(
                        Wt + (size_t)(mi * 32 + droff) * N_DIM + ni * 32);
        }

#pragma unroll
        for (int ks = 0; ks < 4; ++ks) {
            const int p = ks >> 1;
            const int c = (ks & 1) * 2 + half;   // 16B chunk index within row
            bf16x8 af[2], bfr[2];
#pragma unroll
            for (int mi = 0; mi < 2; ++mi) {
                const int R = wy * 64 + mi * 32 + l31;
                const int slot = c ^ ((R >> 1) & 3);
                af[mi] = *reinterpret_cast<const bf16x8*>(
                    Ash + p * 4096 + R * 32 + slot * 8);
            }
#pragma unroll
            for (int ni = 0; ni < 2; ++ni) {
                const int R = wx * 64 + ni * 32 + l31;
                const int slot = c ^ ((R >> 1) & 3);
                bfr[ni] = *reinterpret_cast<const bf16x8*>(
                    Bsh + p * 4096 + R * 32 + slot * 8);
            }
#pragma unroll
            for (int mi = 0; mi < 2; ++mi)
#pragma unroll
                for (int ni = 0; ni < 2; ++ni)
                    acc[mi][ni] = __builtin_amdgcn_mfma_f32_32x32x16_bf16(
                        af[mi], bfr[ni], acc[mi][ni], 0, 0, 0);
        }
        __syncthreads();
    }

    // --- epilogue: C layout 32x32: col(n)=lane&31, row(d)=(reg&3)+8*(reg>>2)+4*half
    // W is already in registers; only B comes from cache (16 KB, L1-resident).
    const int nb = n0 + wx * 64;
    float part0 = 0.f, part1 = 0.f;
#pragma unroll
    for (int mi = 0; mi < 2; ++mi) {
        const int dbase = d0 + wy * 64 + mi * 32 + 4 * half;
#pragma unroll
        for (int reg = 0; reg < 16; ++reg) {
            const int dd = dbase + (reg & 3) + 8 * (reg >> 2);
            const float bd = B[dd];
            part0 += (acc[mi][0][reg] + bd) * wreg[mi][reg][0];
            part1 += (acc[mi][1][reg] + bd) * wreg[mi][reg][1];
        }
    }
    part0 += __shfl_xor(part0, 32);
    part1 += __shfl_xor(part1, 32);
    if (lane < 32) {
        atomicAdd(out + nb + l31, part0);
        atomicAdd(out + nb + 32 + l31, part1);
    }
}

extern "C" void kernel_launch(void* const* d_in, const int* in_sizes, int n_in,
                              void* d_out, int out_size, void* d_ws, size_t ws_size,
                              hipStream_t stream) {
    const float* F = (const float*)d_in[0];   // features (N, K)
    const float* W = (const float*)d_in[1];   // w        (D, N)
    const float* E = (const float*)d_in[2];   // E        (K, D)
    const float* B = (const float*)d_in[3];   // b        (D,)
    float* out = (float*)d_out;               // (N,) f32

    unsigned short* ET = (unsigned short*)d_ws;                       // 4 MB
    unsigned short* FB = (unsigned short*)((char*)d_ws + (size_t)D_DIM * K_DIM * 2);  // 8 MB

    hipMemsetAsync(d_out, 0, (size_t)out_size * sizeof(float), stream);
    transpose_E<<<dim3(D_DIM / 64, K_DIM / 64), 256, 0, stream>>>(E, ET);
    convert_F<<<dim3(N_DIM * K_DIM / (256 * 8)), 256, 0, stream>>>(F, FB);
    gemm_fused<<<dim3(N_DIM / 128, D_DIM / 128), 256, 0, stream>>>(FB, W, ET, B, out);
}

// Round 3
// 237.674 us; speedup vs baseline: 1.0244x; 1.0117x over previous
//
#include <hip/hip_runtime.h>

#define N_DIM 8192   // rows of features / columns of w / output length
#define K_DIM 512    // inner dim of features @ E
#define D_DIM 4096   // columns of E / rows of w

typedef __bf16 bf16x8 __attribute__((ext_vector_type(8)));
typedef float  f32x16 __attribute__((ext_vector_type(16)));
typedef unsigned short u16x8 __attribute__((ext_vector_type(8)));

__device__ __forceinline__ unsigned short f2bf(float f) {
    union { float f; unsigned int u; } v; v.f = f;
    unsigned int r = v.u + 0x7FFF + ((v.u >> 16) & 1);   // RNE
    return (unsigned short)(r >> 16);
}

// ---------------------------------------------------------------------------
// Kernel 1: E [512][4096] f32  ->  ET [4096][512] bf16 (k-contiguous rows)
// ---------------------------------------------------------------------------
__global__ __launch_bounds__(256) void transpose_E(const float* __restrict__ E,
                                                   unsigned short* __restrict__ ET) {
    __shared__ float tile[64][65];
    const int d0 = blockIdx.x * 64;
    const int k0 = blockIdx.y * 64;
    const int tid = threadIdx.x;
    const int r  = tid / 16;          // 0..15
    const int c4 = (tid % 16) * 4;    // 0..60
#pragma unroll
    for (int p = 0; p < 4; ++p) {
        int k = p * 16 + r;
        float4 v = *reinterpret_cast<const float4*>(E + (size_t)(k0 + k) * D_DIM + d0 + c4);
        tile[k][c4 + 0] = v.x; tile[k][c4 + 1] = v.y;
        tile[k][c4 + 2] = v.z; tile[k][c4 + 3] = v.w;
    }
    __syncthreads();
#pragma unroll
    for (int p = 0; p < 4; ++p) {
        int d = p * 16 + r;
        ushort4 o;
        o.x = f2bf(tile[c4 + 0][d]);
        o.y = f2bf(tile[c4 + 1][d]);
        o.z = f2bf(tile[c4 + 2][d]);
        o.w = f2bf(tile[c4 + 3][d]);
        *reinterpret_cast<ushort4*>(ET + (size_t)(d0 + d) * K_DIM + k0 + c4) = o;
    }
}

// ---------------------------------------------------------------------------
// Kernel 2: F [8192][512] f32 -> FB bf16 (k-contiguous rows).
// Blocks 0..7 also zero the 8192-float output (replaces the memset dispatch;
// runs before gemm_fused in stream order).
// ---------------------------------------------------------------------------
__global__ __launch_bounds__(256) void convert_F(const float* __restrict__ F,
                                                 unsigned short* __restrict__ FB,
                                                 float* __restrict__ out) {
    if (blockIdx.x < 8) {
        float4 z = {0.f, 0.f, 0.f, 0.f};
        *reinterpret_cast<float4*>(out + (blockIdx.x * 256 + threadIdx.x) * 4) = z;
    }
    const int idx8 = (blockIdx.x * 256 + threadIdx.x) * 8;
    float4 a = *reinterpret_cast<const float4*>(F + idx8);
    float4 b = *reinterpret_cast<const float4*>(F + idx8 + 4);
    u16x8 o;
    o[0] = f2bf(a.x); o[1] = f2bf(a.y); o[2] = f2bf(a.z); o[3] = f2bf(a.w);
    o[4] = f2bf(b.x); o[5] = f2bf(b.y); o[6] = f2bf(b.z); o[7] = f2bf(b.w);
    *reinterpret_cast<u16x8*>(FB + idx8) = o;
}

// ---------------------------------------------------------------------------
// Kernel 3: fused  out[n] = sum_d (F@E + b)[n,d] * w[d,n], computed as y^T:
// C-tile 128(d-rows) x 128(n-cols), BK=64, 4 waves (2x2), 32x32x16 bf16 MFMA.
//
// Round 3: RAW barriers + counted vmcnt (T4). __syncthreads' fence semantics
// emit s_waitcnt vmcnt(0) before s_barrier, draining the in-flight W loads
// every kt (why R1/R2 were neutral). Now per kt: issue 8 staging gload_lds,
// fence, issue 8 NT W loads, s_waitcnt vmcnt(8) (staging done, W stays in
// flight ACROSS the raw barrier), compute, raw barrier. W's HBM latency
// hides under MFMA; epilogue is register-only. sched_barrier(0) sandwiches
// pin each phase (no ds_read/MFMA may sink past the reuse barrier; no
// gload_lds may hoist above it).
// ---------------------------------------------------------------------------
__global__ __launch_bounds__(256, 2) void gemm_fused(const unsigned short* __restrict__ FB,
                                                     const float* __restrict__ W,
                                                     const unsigned short* __restrict__ ET,
                                                     const float* __restrict__ B,
                                                     float* __restrict__ out) {
    __shared__ unsigned short Ash[2 * 128 * 32];  // ET tile: rows = d  (16 KB)
    __shared__ unsigned short Bsh[2 * 128 * 32];  // FB tile: rows = n  (16 KB)

    const int tid  = threadIdx.x;
    const int wave = tid >> 6;
    const int lane = tid & 63;
    const int wy   = wave >> 1;     // d-direction wave coord (0..1)
    const int wx   = wave & 1;      // n-direction wave coord (0..1)
    const int l31  = lane & 31;
    const int half = lane >> 5;

    // --- XCD-rectangle swizzle (bijection on 64x32 grid) ---
    const int f   = blockIdx.x + ((int)gridDim.x) * blockIdx.y;  // dispatch order
    const int xcd = f & 7;
    const int s   = f >> 3;               // 0..255 within XCD
    const int ntile = (xcd & 3) * 16 + (s & 15);   // 0..63
    const int dtile = (xcd >> 2) * 16 + (s >> 4);  // 0..31
    const int n0 = ntile * 128;
    const int d0 = dtile * 128;

    f32x16 acc[2][2] = {};       // [mi=d-tile][ni=n-tile]
    float  wreg[2][16][2];       // [mi][reg][ni] -- W values for this thread's acc

    // Per-thread W base: row = d0 + wy*64 + 4*half, col = n0 + wx*64 + l31.
    const float* Wt = W + (size_t)(d0 + wy * 64 + 4 * half) * N_DIM + n0 + wx * 64 + l31;

    // staging: one global_load_lds(16B) covers 16 rows x 64 B
    const int srow   = lane >> 2;                               // 0..15
    const int schunk = (((lane & 3) ^ ((srow >> 1) & 3)) * 8);  // swizzled chunk (shorts)

#pragma unroll
    for (int kt = 0; kt < K_DIM / 64; ++kt) {
        const int kb = kt * 64;
        // ---- phase 1: staging issue (8 gload_lds per wave), MUST precede W ----
#pragma unroll
        for (int p = 0; p < 2; ++p) {
#pragma unroll
            for (int jj = 0; jj < 2; ++jj) {
                const int j = wave * 2 + jj;   // 0..7 -> 16 rows each
                const unsigned short* ga =
                    ET + (size_t)(d0 + j * 16 + srow) * K_DIM + kb + p * 32 + schunk;
                __builtin_amdgcn_global_load_lds(
                    (const __attribute__((address_space(1))) void*)ga,
                    (__attribute__((address_space(3))) void*)(Ash + p * 4096 + j * 512),
                    16, 0, 0);
                const unsigned short* gb =
                    FB + (size_t)(n0 + j * 16 + srow) * K_DIM + kb + p * 32 + schunk;
                __builtin_amdgcn_global_load_lds(
                    (const __attribute__((address_space(1))) void*)gb,
                    (__attribute__((address_space(3))) void*)(Bsh + p * 4096 + j * 512),
                    16, 0, 0);
            }
        }
        asm volatile("" ::: "memory");   // order: all staging before any W load

        // ---- phase 2: this kt's 8 W loads (land during MFMA / next kt) ----
#pragma unroll
        for (int rr = 0; rr < 2; ++rr) {
            const int reg   = kt * 2 + rr;
            const int droff = (reg & 3) + 8 * (reg >> 2);
#pragma unroll
            for (int mi = 0; mi < 2; ++mi)
#pragma unroll
                for (int ni = 0; ni < 2; ++ni)
                    wreg[mi][reg][ni] = __builtin_nontemporal_load(
                        Wt + (size_t)(mi * 32 + droff) * N_DIM + ni * 32);
        }
        asm volatile("" ::: "memory");   // order: W loads issued before the wait

        // ---- counted wait: staging complete, W (8 newest) stays in flight ----
        asm volatile("s_waitcnt vmcnt(8)" ::: "memory");
        __builtin_amdgcn_sched_barrier(0);
        __builtin_amdgcn_s_barrier();            // raw: no vmcnt(0) drain
        __builtin_amdgcn_sched_barrier(0);

        // ---- phase 3: ds_read + MFMA (compiler manages lgkmcnt) ----
#pragma unroll
        for (int ks = 0; ks < 4; ++ks) {
            const int p = ks >> 1;
            const int c = (ks & 1) * 2 + half;   // 16B chunk index within row
            bf16x8 af[2], bfr[2];
#pragma unroll
            for (int mi = 0; mi < 2; ++mi) {
                const int R = wy * 64 + mi * 32 + l31;
                const int slot = c ^ ((R >> 1) & 3);
                af[mi] = *reinterpret_cast<const bf16x8*>(
                    Ash + p * 4096 + R * 32 + slot * 8);
            }
#pragma unroll
            for (int ni = 0; ni < 2; ++ni) {
                const int R = wx * 64 + ni * 32 + l31;
                const int slot = c ^ ((R >> 1) & 3);
                bfr[ni] = *reinterpret_cast<const bf16x8*>(
                    Bsh + p * 4096 + R * 32 + slot * 8);
            }
#pragma unroll
            for (int mi = 0; mi < 2; ++mi)
#pragma unroll
                for (int ni = 0; ni < 2; ++ni)
                    acc[mi][ni] = __builtin_amdgcn_mfma_f32_32x32x16_bf16(
                        af[mi], bfr[ni], acc[mi][ni], 0, 0, 0);
        }

        // ---- reuse barrier: pin compute above, next staging below ----
        __builtin_amdgcn_sched_barrier(0);
        __builtin_amdgcn_s_barrier();            // raw: W loads survive it
        __builtin_amdgcn_sched_barrier(0);
    }

    // --- epilogue: C layout 32x32: col(n)=lane&31, row(d)=(reg&3)+8*(reg>>2)+4*half
    // W already in registers (compiler inserts the final vmcnt wait before use).
    const int nb = n0 + wx * 64;
    float part0 = 0.f, part1 = 0.f;
#pragma unroll
    for (int mi = 0; mi < 2; ++mi) {
        const int dbase = d0 + wy * 64 + mi * 32 + 4 * half;
#pragma unroll
        for (int reg = 0; reg < 16; ++reg) {
            const int dd = dbase + (reg & 3) + 8 * (reg >> 2);
            const float bd = B[dd];
            part0 += (acc[mi][0][reg] + bd) * wreg[mi][reg][0];
            part1 += (acc[mi][1][reg] + bd) * wreg[mi][reg][1];
        }
    }
    part0 += __shfl_xor(part0, 32);
    part1 += __shfl_xor(part1, 32);
    if (lane < 32) {
        atomicAdd(out + nb + l31, part0);
        atomicAdd(out + nb + 32 + l31, part1);
    }
}

extern "C" void kernel_launch(void* const* d_in, const int* in_sizes, int n_in,
                              void* d_out, int out_size, void* d_ws, size_t ws_size,
                              hipStream_t stream) {
    const float* F = (const float*)d_in[0];   // features (N, K)
    const float* W = (const float*)d_in[1];   // w        (D, N)
    const float* E = (const float*)d_in[2];   // E        (K, D)
    const float* B = (const float*)d_in[3];   // b        (D,)
    float* out = (float*)d_out;               // (N,) f32

    unsigned short* ET = (unsigned short*)d_ws;                       // 4 MB
    unsigned short* FB = (unsigned short*)((char*)d_ws + (size_t)D_DIM * K_DIM * 2);  // 8 MB

    transpose_E<<<dim3(D_DIM / 64, K_DIM / 64), 256, 0, stream>>>(E, ET);
    convert_F<<<dim3(N_DIM * K_DIM / (256 * 8)), 256, 0, stream>>>(F, FB, out);
    gemm_fused<<<dim3(N_DIM / 128, D_DIM / 128), 256, 0, stream>>>(FB, W, ET, B, out);
}